// Round 4
// baseline (32231.241 us; speedup 1.0000x reference)
//
#include <hip/hip_runtime.h>

#define S_LEN 8192
#define KREL 8
#define WPD 128  // workgroups per direction; each owns 512/WPD = 4 h-columns

typedef float f4 __attribute__((ext_vector_type(4)));
typedef unsigned long long u64;

__device__ __forceinline__ float sigmf(float x) { return 1.0f / (1.0f + __expf(-x)); }
__device__ __forceinline__ float tanhfast(float x) { return 1.0f - 2.0f / (__expf(2.0f * x) + 1.0f); }

// ---------------- mask canonicalization (R2-verified) ----------------
__global__ void k_maskcvt(const unsigned char* __restrict__ src,
                          unsigned char* __restrict__ dst, int n)
{
  const unsigned int* w = (const unsigned int*)src;
  __shared__ int s_i32, s_f32;
  if (threadIdx.x == 0) { s_i32 = 1; s_f32 = 1; }
  __syncthreads();
  int i32ok = 1, f32ok = 1;
  for (int i = threadIdx.x; i < 1024; i += blockDim.x) {
    const unsigned int v = w[i];
    if (v != 0u && v != 1u) i32ok = 0;
    if (v != 0u && v != 0x3F800000u) f32ok = 0;
  }
  if (!i32ok) atomicAnd(&s_i32, 0);
  if (!f32ok) atomicAnd(&s_f32, 0);
  __syncthreads();
  const int wide = (s_i32 || s_f32);
  for (int i = blockIdx.x * blockDim.x + threadIdx.x; i < n; i += gridDim.x * blockDim.x)
    dst[i] = wide ? (w[i] ? 1 : 0) : (src[i] ? 1 : 0);
}

// ---------------- parallel precompute (R2-verified) ----------------
__global__ __launch_bounds__(256)
void k_gemm(const float* __restrict__ X, const float* __restrict__ Wioux,
            const float* __restrict__ Wlx, const float* __restrict__ bioux,
            const float* __restrict__ biouh, const float* __restrict__ blx,
            const float* __restrict__ blh, float* __restrict__ P)
{
  __shared__ float As[16][64];
  __shared__ float Bs[16][64];
  const int t0 = blockIdx.x * 64;
  const int r0 = blockIdx.y * 64;
  const int tid = threadIdx.x;
  const int tx = tid & 15, ty = tid >> 4;
  const int si = tid >> 2, sk = (tid & 3) << 2;
  const int rB = r0 + si;
  const float* brow = (rB < 2560) ? (Wioux + (size_t)rB * 512)
                                  : (Wlx + (size_t)(rB - 2560) * 512);
  const float* arow = X + (size_t)(t0 + si) * 512;
  float acc[4][4] = {};
  for (int k0 = 0; k0 < 512; k0 += 16) {
    const float4 av = *(const float4*)(arow + k0 + sk);
    const float4 bv = *(const float4*)(brow + k0 + sk);
    __syncthreads();
    As[sk + 0][si] = av.x; As[sk + 1][si] = av.y; As[sk + 2][si] = av.z; As[sk + 3][si] = av.w;
    Bs[sk + 0][si] = bv.x; Bs[sk + 1][si] = bv.y; Bs[sk + 2][si] = bv.z; Bs[sk + 3][si] = bv.w;
    __syncthreads();
#pragma unroll
    for (int kk = 0; kk < 16; ++kk) {
      const float4 a = *(const float4*)&As[kk][ty * 4];
      const float4 b = *(const float4*)&Bs[kk][tx * 4];
      acc[0][0] += a.x * b.x; acc[0][1] += a.x * b.y; acc[0][2] += a.x * b.z; acc[0][3] += a.x * b.w;
      acc[1][0] += a.y * b.x; acc[1][1] += a.y * b.y; acc[1][2] += a.y * b.z; acc[1][3] += a.y * b.w;
      acc[2][0] += a.z * b.x; acc[2][1] += a.z * b.y; acc[2][2] += a.z * b.z; acc[2][3] += a.z * b.w;
      acc[3][0] += a.w * b.x; acc[3][1] += a.w * b.y; acc[3][2] += a.w * b.z; acc[3][3] += a.w * b.w;
    }
  }
#pragma unroll
  for (int i = 0; i < 4; ++i) {
    const int t = t0 + ty * 4 + i;
#pragma unroll
    for (int j = 0; j < 4; ++j) {
      const int r = r0 + tx * 4 + j;
      const float bias = (r < 2560) ? (bioux[r] + biouh[r]) : (blx[r - 2560] + blh[r - 2560]);
      P[(size_t)t * 3072 + r] = acc[i][j] + bias;
    }
  }
}

// ---------------- persistent recurrent kernel v10 ----------------
// v9 (verified, 17.38ms) with ONE scheduling change: the next-step prefetch
// loads (out[jjN], Gbuf[jjN], lb[depN], 6 P-row floats, t2 indices) are
// issued INSIDE phase (B) -- after the initial rolling-poll batch, before
// the spin -- pinned with sched_barrier(0) on both sides. Rationale: vmcnt
// retires FIFO, so v9's end-of-step prefetch (several random-access loads
// at IC/HBM latency, 450-900cyc) was drained by the NEXT step's first
// poll-sample wait ~50cyc later, exposing nearly the full latency on the
// discovery path every step. Now the spin (and the lgkm-gated LDS spin,
// vmcnt-independent) absorbs it; commits at loop bottom are register moves.
// Hazard audit: newly-shortened RAW windows are Gbuf[t(s-2)] / out[t(s-1)]
// written by the SAME wave at (E,s-1), read ~0.5-1 step later -- same-CU
// write-through + L1 invalidation covers; jj==prevt/prevt2 register patches
// cover all fresher cases (unchanged from v9).
__global__ __launch_bounds__(256, 1)
void k_rec(const float* __restrict__ Wiouh, const float* __restrict__ Wlh,
           const float* __restrict__ P, const float* __restrict__ lb,
           const int* __restrict__ rel_fw, const int* __restrict__ dep_fw,
           const unsigned char* __restrict__ mask_fw,
           const int* __restrict__ rel_bw, const int* __restrict__ dep_bw,
           const unsigned char* __restrict__ mask_bw,
           float* __restrict__ Gfw, float* __restrict__ Gbw,
           u64* rec, float* __restrict__ out)
{
  __shared__ u64 hsp[2][2][4][64];   // 8 KB: [parity][half][j][slot] perm packets
  const int wg  = blockIdx.x;
  const int dir = wg / WPD;
  const int w   = wg % WPD;
  const int tid = threadIdx.x;
  const int grp = tid >> 6;            // 4 column-groups per WG (one wave each)
  const int lane = tid & 63;           // 64 lanes per column
  const int kl = lane & 7;             // owned relative slot (8 octets duplicate)
  const int m = w * 4 + grp;           // owned h-column
  const int dircol = dir * 512;
  const int* rel = dir ? rel_bw : rel_fw;
  const int* dep = dir ? dep_bw : dep_fw;
  const unsigned char* msk = dir ? mask_bw : mask_fw;
  float* Gbuf = dir ? Gbw : Gfw;

  // ---- one-time weight load into REGISTERS (48 VGPRs, loop-invariant) ----
  f4 wreg[6][2];
  {
    const float* rows[6];
#pragma unroll
    for (int rg = 0; rg < 5; ++rg) rows[rg] = Wiouh + (size_t)(rg * 512 + m) * 512;
    rows[5] = Wlh + (size_t)m * 512;
#pragma unroll
    for (int rg = 0; rg < 6; ++rg)
#pragma unroll
      for (int q = 0; q < 2; ++q)
        wreg[rg][q] = *(const f4*)(rows[rg] + q * 256 + lane * 4);
  }

  // zero both packet parities: step 0 passes the spin on tag==0 with h==0
  {
    u64* hz = (u64*)hsp;
    hz[tid] = 0ull; hz[tid + 256] = 0ull; hz[tid + 512] = 0ull; hz[tid + 768] = 0ull;
  }

  float cstate = 0.0f, hprev = 0.0f, gprev = 0.0f;

  // ---- prologue: step-0 gathers (dead: first step fully masked) + step-1 indices ----
  int jjU, mkU, jjN, mkN, depN;
  float Hg, Gg, LBg;
  float p0, p1, p2, p3, p4, p5;
  {
    const int t0 = dir ? (S_LEN - 1) : 0;
    const int t1 = dir ? (S_LEN - 2) : 1;
    jjU = rel[t0 * KREL + kl]; mkU = (int)msk[t0 * KREL + kl];
    Hg  = out[(size_t)jjU * 1024 + dircol + m];
    Gg  = Gbuf[(size_t)jjU * 512 + m];
    LBg = lb[(size_t)dep[t0 * KREL + kl] * 512 + m];
    const float* prow = P + (size_t)t0 * 3072;
    p0 = prow[m];        p1 = prow[512 + m];  p2 = prow[1024 + m];
    p3 = prow[1536 + m]; p4 = prow[2048 + m]; p5 = prow[2560 + m];
    jjN = rel[t1 * KREL + kl]; mkN = (int)msk[t1 * KREL + kl]; depN = dep[t1 * KREL + kl];
  }
  __syncthreads();   // packet LDS zeroed (only barrier in the kernel)

#pragma unroll 1
  for (int s = 0; s < S_LEN; ++s) {
    const int t = dir ? (S_LEN - 1 - s) : s;
    const int tn = dir ? (t - 1) : (t + 1);
    const int prevt  = dir ? (t + 1) : (t - 1);   // matches jj only when s>0
    const int prevt2 = dir ? (t + 2) : (t - 2);
    const int par = s & 1;

    // ---- (A2) precompute relative-agg term for the jj != prevt case ----
    const float gv_base = (jjU == prevt2) ? gprev : Gg;
    const float sm_pre  = mkU ? (sigmf(gv_base + p5 + LBg) * Hg) : 0.0f;

    // ---- (B0) initial rolling-poll batch (issued FIRST: oldest in FIFO) ----
    u64 a0 = 0, a1 = 0, b0 = 0, b1 = 0, c0 = 0, c1 = 0;
    u64 *q0 = 0, *q1 = 0;
    if (s > 0) {
      const int pb = (((s - 1) & 1) * 2 + dir) * 512;
      q0 = rec + pb + tid;
      q1 = rec + pb + tid + 256;
      a0 = __hip_atomic_load(q0, __ATOMIC_RELAXED, __HIP_MEMORY_SCOPE_AGENT);
      a1 = __hip_atomic_load(q1, __ATOMIC_RELAXED, __HIP_MEMORY_SCOPE_AGENT);
      b0 = __hip_atomic_load(q0, __ATOMIC_RELAXED, __HIP_MEMORY_SCOPE_AGENT);
      b1 = __hip_atomic_load(q1, __ATOMIC_RELAXED, __HIP_MEMORY_SCOPE_AGENT);
      c0 = __hip_atomic_load(q0, __ATOMIC_RELAXED, __HIP_MEMORY_SCOPE_AGENT);
      c1 = __hip_atomic_load(q1, __ATOMIC_RELAXED, __HIP_MEMORY_SCOPE_AGENT);
    }
    __builtin_amdgcn_sched_barrier(0);

    // ---- (PF) issue next-step prefetch loads NOW (fly during the spin) ----
    float HgN = 0.0f, GgN = 0.0f, LBgN = 0.0f;
    float n0 = 0, n1 = 0, n2 = 0, n3 = 0, n4 = 0, n5 = 0;
    int jj2 = jjN, mk2 = mkN, dep2 = depN;
    if (s < S_LEN - 1) {
      HgN  = out[(size_t)jjN * 1024 + dircol + m];
      GgN  = Gbuf[(size_t)jjN * 512 + m];
      LBgN = lb[(size_t)depN * 512 + m];
      const float* prow = P + (size_t)tn * 3072;
      n0 = prow[m];        n1 = prow[512 + m];  n2 = prow[1024 + m];
      n3 = prow[1536 + m]; n4 = prow[2048 + m]; n5 = prow[2560 + m];
      if (s < S_LEN - 2) {
        const int t2 = dir ? (t - 2) : (t + 2);
        jj2 = rel[t2 * KREL + kl]; mk2 = (int)msk[t2 * KREL + kl]; dep2 = dep[t2 * KREL + kl];
      }
    }
    __builtin_amdgcn_sched_barrier(0);

    // ---- (B1) rolling depth-3 spin -> perm LDS slots ----
    if (s > 0) {
      for (;;) {
        const bool k0 = (unsigned)(a0 >> 32) >= (unsigned)s;
        const bool k1 = (unsigned)(a1 >> 32) >= (unsigned)s;
        if (k0 && k1) break;
        const u64 m0 = __hip_atomic_load(q0, __ATOMIC_RELAXED, __HIP_MEMORY_SCOPE_AGENT);
        const u64 m1 = __hip_atomic_load(q1, __ATOMIC_RELAXED, __HIP_MEMORY_SCOPE_AGENT);
        a0 = k0 ? a0 : b0;  b0 = k0 ? b0 : c0;  c0 = m0;
        a1 = k1 ? a1 : b1;  b1 = k1 ? b1 : c1;  c1 = m1;
      }
      __hip_atomic_store(&hsp[par][0][tid & 3][tid >> 2], a0,
                         __ATOMIC_RELAXED, __HIP_MEMORY_SCOPE_WORKGROUP);
      __hip_atomic_store(&hsp[par][1][tid & 3][tid >> 2], a1,
                         __ATOMIC_RELAXED, __HIP_MEMORY_SCOPE_WORKGROUP);
    }

    // ---- (B2) per-lane spin on the 8 perm packets (4-way b64, lgkm-gated) ----
    u64 pk0[4], pk1[4];
    for (;;) {
      unsigned mn = 0xffffffffu;
#pragma unroll
      for (int j = 0; j < 4; ++j) {
        pk0[j] = __hip_atomic_load(&hsp[par][0][j][lane],
                                   __ATOMIC_RELAXED, __HIP_MEMORY_SCOPE_WORKGROUP);
        pk1[j] = __hip_atomic_load(&hsp[par][1][j][lane],
                                   __ATOMIC_RELAXED, __HIP_MEMORY_SCOPE_WORKGROUP);
        const unsigned t0 = (unsigned)(pk0[j] >> 32);
        const unsigned t1 = (unsigned)(pk1[j] >> 32);
        mn = mn < t0 ? mn : t0;
        mn = mn < t1 ? mn : t1;
      }
      if (mn >= (unsigned)s) break;
    }

    // ---- (C) dots: 6 owned rows x 8 elems/lane, butterfly over 64 lanes ----
    float hx0[4], hx1[4];
#pragma unroll
    for (int j = 0; j < 4; ++j) {
      hx0[j] = __uint_as_float((unsigned)pk0[j]);
      hx1[j] = __uint_as_float((unsigned)pk1[j]);
    }
    float dsum[6];
#pragma unroll
    for (int rg = 0; rg < 6; ++rg) {
      float a = 0.0f;
#pragma unroll
      for (int j = 0; j < 4; ++j) {
        a += wreg[rg][0][j] * hx0[j];
        a += wreg[rg][1][j] * hx1[j];
      }
      a += __shfl_xor(a, 1);  a += __shfl_xor(a, 2);  a += __shfl_xor(a, 4);
      a += __shfl_xor(a, 8);  a += __shfl_xor(a, 16); a += __shfl_xor(a, 32);
      dsum[rg] = a;            // full sum in ALL 64 lanes
    }
    const float g = dsum[5];   // Wlh @ h_prev = G[prevt]

    // ---- (D) gates + relative aggregation (identical on all lanes) ----
    const float iv = sigmf(p0 + dsum[0]);
    const float ov = sigmf(p1 + dsum[1]);
    const float sv = sigmf(p2 + dsum[2]);
    const float fv = sigmf(p3 + dsum[3]);
    const float uv = tanhfast(p4 + dsum[4]);
    cstate = fv * cstate + iv * uv;
    const float hb = ov * tanhfast(cstate);

    const float smf = mkU ? (sigmf(g + p5 + LBg) * hprev) : 0.0f;  // jj==prevt patch
    float sm = (jjU == prevt) ? smf : sm_pre;
    sm += __shfl_xor(sm, 1); sm += __shfl_xor(sm, 2); sm += __shfl_xor(sm, 4);
    const float hval = hb + sv * tanhfast(sm);

    // ---- (E) publish first (critical path), then plain stores ----
    if (lane == 0) {
      const u64 pk =
          ((u64)(unsigned)(s + 1) << 32) | (u64)__float_as_uint(hval);
      __hip_atomic_store(rec + ((s & 1) * 2 + dir) * 512 + m, pk,
                         __ATOMIC_RELAXED, __HIP_MEMORY_SCOPE_AGENT);
      out[(size_t)t * 1024 + dircol + m] = hval;
      if (s > 0) Gbuf[(size_t)prevt * 512 + m] = g;
    }

    // ---- (F') commit prefetched state (pure register moves) ----
    if (s < S_LEN - 1) {
      jjU = jjN; mkU = mkN; Hg = HgN; Gg = GgN; LBg = LBgN;
      p0 = n0; p1 = n1; p2 = n2; p3 = n3; p4 = n4; p5 = n5;
      jjN = jj2; mkN = mk2; depN = dep2;
    }
    hprev = hval; gprev = g;
  }
}

__global__ void k_fill(float* __restrict__ o, int n, float v)
{ const int i = blockIdx.x * 256 + threadIdx.x; if (i < n) o[i] = v; }

extern "C" void kernel_launch(void* const* d_in, const int* in_sizes, int n_in,
                              void* d_out, int out_size, void* d_ws, size_t ws_size,
                              hipStream_t stream)
{
  (void)in_sizes; (void)n_in;
  const float* X     = (const float*)d_in[0];
  const float* Wioux = (const float*)d_in[1];
  const float* bioux = (const float*)d_in[2];
  const float* Wiouh = (const float*)d_in[3];
  const float* biouh = (const float*)d_in[4];
  const float* Wlx   = (const float*)d_in[5];
  const float* blx   = (const float*)d_in[6];
  const float* Wlh   = (const float*)d_in[7];
  const float* blh   = (const float*)d_in[8];
  const float* lb    = (const float*)d_in[9];
  const int* rel_fw  = (const int*)d_in[10];
  const int* dep_fw  = (const int*)d_in[11];
  const unsigned char* mask_fw_raw = (const unsigned char*)d_in[12];
  const int* rel_bw  = (const int*)d_in[13];
  const int* dep_bw  = (const int*)d_in[14];
  const unsigned char* mask_bw_raw = (const unsigned char*)d_in[15];
  float* out = (float*)d_out;

  const int nmask = S_LEN * KREL;                  // 65536
  const size_t needP = (size_t)S_LEN * 3072 * 4;   // 96 MB
  const size_t needG = (size_t)S_LEN * 512 * 4;    // 16 MB each
  const size_t need  = 32768 + needP + 2 * needG + 2 * (size_t)nmask;
  if (ws_size < need) {
    k_fill<<<(out_size + 255) / 256, 256, 0, stream>>>(out, out_size, 12345.0f);
    return;
  }
  char* ws = (char*)d_ws;
  u64*   rec = (u64*)ws;                   // [2 buf][2 dir][512] packets
  float* P   = (float*)(ws + 32768);
  float* Gfw = (float*)(ws + 32768 + needP);
  float* Gbw = Gfw + (size_t)S_LEN * 512;
  unsigned char* Mfw = (unsigned char*)(ws + 32768 + needP + 2 * needG);
  unsigned char* Mbw = Mfw + nmask;

  hipMemsetAsync(rec, 0, 16384, stream);   // tags must start at 0 (ws poisoned 0xAA)
  k_maskcvt<<<64, 256, 0, stream>>>(mask_fw_raw, Mfw, nmask);
  k_maskcvt<<<64, 256, 0, stream>>>(mask_bw_raw, Mbw, nmask);
  dim3 gg(S_LEN / 64, 3072 / 64);
  k_gemm<<<gg, 256, 0, stream>>>(X, Wioux, Wlx, bioux, biouh, blx, blh, P);
  k_rec<<<2 * WPD, 256, 0, stream>>>(Wiouh, Wlh, P, lb, rel_fw, dep_fw, Mfw,
                                     rel_bw, dep_bw, Mbw, Gfw, Gbw, rec, out);
}

// Round 5
// 17196.313 us; speedup vs baseline: 1.8743x; 1.8743x over previous
//
#include <hip/hip_runtime.h>

#define S_LEN 8192
#define KREL 8
#define WPD 128  // workgroups per direction; each owns 512/WPD = 4 h-columns

typedef float f4 __attribute__((ext_vector_type(4)));
typedef unsigned long long u64;

__device__ __forceinline__ float sigmf(float x) { return 1.0f / (1.0f + __expf(-x)); }
__device__ __forceinline__ float tanhfast(float x) { return 1.0f - 2.0f / (__expf(2.0f * x) + 1.0f); }

// ---------------- mask canonicalization (R2-verified) ----------------
__global__ void k_maskcvt(const unsigned char* __restrict__ src,
                          unsigned char* __restrict__ dst, int n)
{
  const unsigned int* w = (const unsigned int*)src;
  __shared__ int s_i32, s_f32;
  if (threadIdx.x == 0) { s_i32 = 1; s_f32 = 1; }
  __syncthreads();
  int i32ok = 1, f32ok = 1;
  for (int i = threadIdx.x; i < 1024; i += blockDim.x) {
    const unsigned int v = w[i];
    if (v != 0u && v != 1u) i32ok = 0;
    if (v != 0u && v != 0x3F800000u) f32ok = 0;
  }
  if (!i32ok) atomicAnd(&s_i32, 0);
  if (!f32ok) atomicAnd(&s_f32, 0);
  __syncthreads();
  const int wide = (s_i32 || s_f32);
  for (int i = blockIdx.x * blockDim.x + threadIdx.x; i < n; i += gridDim.x * blockDim.x)
    dst[i] = wide ? (w[i] ? 1 : 0) : (src[i] ? 1 : 0);
}

// ---------------- parallel precompute (R2-verified) ----------------
__global__ __launch_bounds__(256)
void k_gemm(const float* __restrict__ X, const float* __restrict__ Wioux,
            const float* __restrict__ Wlx, const float* __restrict__ bioux,
            const float* __restrict__ biouh, const float* __restrict__ blx,
            const float* __restrict__ blh, float* __restrict__ P)
{
  __shared__ float As[16][64];
  __shared__ float Bs[16][64];
  const int t0 = blockIdx.x * 64;
  const int r0 = blockIdx.y * 64;
  const int tid = threadIdx.x;
  const int tx = tid & 15, ty = tid >> 4;
  const int si = tid >> 2, sk = (tid & 3) << 2;
  const int rB = r0 + si;
  const float* brow = (rB < 2560) ? (Wioux + (size_t)rB * 512)
                                  : (Wlx + (size_t)(rB - 2560) * 512);
  const float* arow = X + (size_t)(t0 + si) * 512;
  float acc[4][4] = {};
  for (int k0 = 0; k0 < 512; k0 += 16) {
    const float4 av = *(const float4*)(arow + k0 + sk);
    const float4 bv = *(const float4*)(brow + k0 + sk);
    __syncthreads();
    As[sk + 0][si] = av.x; As[sk + 1][si] = av.y; As[sk + 2][si] = av.z; As[sk + 3][si] = av.w;
    Bs[sk + 0][si] = bv.x; Bs[sk + 1][si] = bv.y; Bs[sk + 2][si] = bv.z; Bs[sk + 3][si] = bv.w;
    __syncthreads();
#pragma unroll
    for (int kk = 0; kk < 16; ++kk) {
      const float4 a = *(const float4*)&As[kk][ty * 4];
      const float4 b = *(const float4*)&Bs[kk][tx * 4];
      acc[0][0] += a.x * b.x; acc[0][1] += a.x * b.y; acc[0][2] += a.x * b.z; acc[0][3] += a.x * b.w;
      acc[1][0] += a.y * b.x; acc[1][1] += a.y * b.y; acc[1][2] += a.y * b.z; acc[1][3] += a.y * b.w;
      acc[2][0] += a.z * b.x; acc[2][1] += a.z * b.y; acc[2][2] += a.z * b.z; acc[2][3] += a.z * b.w;
      acc[3][0] += a.w * b.x; acc[3][1] += a.w * b.y; acc[3][2] += a.w * b.z; acc[3][3] += a.w * b.w;
    }
  }
#pragma unroll
  for (int i = 0; i < 4; ++i) {
    const int t = t0 + ty * 4 + i;
#pragma unroll
    for (int j = 0; j < 4; ++j) {
      const int r = r0 + tx * 4 + j;
      const float bias = (r < 2560) ? (bioux[r] + biouh[r]) : (blx[r - 2560] + blh[r - 2560]);
      P[(size_t)t * 3072 + r] = acc[i][j] + bias;
    }
  }
}

// ---------------- persistent recurrent kernel v11 ----------------
// EXACT v9 structure (verified best: 17.38ms; v10's prefetch reordering
// regressed 85% -- its sched_barrier fences pinned dependent arithmetic of
// the prefetch loads before the spin, serializing a full miss latency per
// step; reverted). ONE change vs v9: s_sleep(2) backoff on the MISS path of
// the global poll spin. Rationale (counter evidence): FETCH_SIZE 2.9GB vs
// ~250MB algorithmic ideal -> ~2.6GB is poll traffic, concentrated on the
// 32 active rec lines; 128 WGs/direction x 512 slots x 3-6 samples/step of
// agent-scope loads serialize at the IC (L2 non-coherent -> every sample is
// an IC access) -> thousands of cycles/step of queueing. Backoff cuts
// sampling rate ~2-3x for <=128cyc worst-case added discovery delay.
// Success path (tag already arrived) pays nothing.
// Skew safety: identical induction to v9 -- LDS packet tags double as
// per-wave progress proof; a wave reaches step s+2 (overwriting parity s&1)
// only after all local waves' step-s+1 LDS writes, which postdate their
// parity-s&1 reads at step s. Packets are 8B tear-free; tags monotone.
__global__ __launch_bounds__(256, 1)
void k_rec(const float* __restrict__ Wiouh, const float* __restrict__ Wlh,
           const float* __restrict__ P, const float* __restrict__ lb,
           const int* __restrict__ rel_fw, const int* __restrict__ dep_fw,
           const unsigned char* __restrict__ mask_fw,
           const int* __restrict__ rel_bw, const int* __restrict__ dep_bw,
           const unsigned char* __restrict__ mask_bw,
           float* __restrict__ Gfw, float* __restrict__ Gbw,
           u64* rec, float* __restrict__ out)
{
  __shared__ u64 hsp[2][2][4][64];   // 8 KB: [parity][half][j][slot] perm packets
  const int wg  = blockIdx.x;
  const int dir = wg / WPD;
  const int w   = wg % WPD;
  const int tid = threadIdx.x;
  const int grp = tid >> 6;            // 4 column-groups per WG (one wave each)
  const int lane = tid & 63;           // 64 lanes per column
  const int kl = lane & 7;             // owned relative slot (8 octets duplicate)
  const int m = w * 4 + grp;           // owned h-column
  const int dircol = dir * 512;
  const int* rel = dir ? rel_bw : rel_fw;
  const int* dep = dir ? dep_bw : dep_fw;
  const unsigned char* msk = dir ? mask_bw : mask_fw;
  float* Gbuf = dir ? Gbw : Gfw;

  // ---- one-time weight load into REGISTERS (48 VGPRs, loop-invariant) ----
  f4 wreg[6][2];
  {
    const float* rows[6];
#pragma unroll
    for (int rg = 0; rg < 5; ++rg) rows[rg] = Wiouh + (size_t)(rg * 512 + m) * 512;
    rows[5] = Wlh + (size_t)m * 512;
#pragma unroll
    for (int rg = 0; rg < 6; ++rg)
#pragma unroll
      for (int q = 0; q < 2; ++q)
        wreg[rg][q] = *(const f4*)(rows[rg] + q * 256 + lane * 4);
  }

  // zero both packet parities: step 0 passes the spin on tag==0 with h==0
  {
    u64* hz = (u64*)hsp;
    hz[tid] = 0ull; hz[tid + 256] = 0ull; hz[tid + 512] = 0ull; hz[tid + 768] = 0ull;
  }

  float cstate = 0.0f, hprev = 0.0f, gprev = 0.0f;

  // ---- prologue: step-0 gathers (dead: first step fully masked) + step-1 indices ----
  int jjU, mkU, jjN, mkN, depN;
  float Hg, Gg, LBg;
  float p0, p1, p2, p3, p4, p5;
  {
    const int t0 = dir ? (S_LEN - 1) : 0;
    const int t1 = dir ? (S_LEN - 2) : 1;
    jjU = rel[t0 * KREL + kl]; mkU = (int)msk[t0 * KREL + kl];
    Hg  = out[(size_t)jjU * 1024 + dircol + m];
    Gg  = Gbuf[(size_t)jjU * 512 + m];
    LBg = lb[(size_t)dep[t0 * KREL + kl] * 512 + m];
    const float* prow = P + (size_t)t0 * 3072;
    p0 = prow[m];        p1 = prow[512 + m];  p2 = prow[1024 + m];
    p3 = prow[1536 + m]; p4 = prow[2048 + m]; p5 = prow[2560 + m];
    jjN = rel[t1 * KREL + kl]; mkN = (int)msk[t1 * KREL + kl]; depN = dep[t1 * KREL + kl];
  }
  __syncthreads();   // packet LDS zeroed (only barrier in the kernel)

#pragma unroll 1
  for (int s = 0; s < S_LEN; ++s) {
    const int t = dir ? (S_LEN - 1 - s) : s;
    const int tn = dir ? (t - 1) : (t + 1);
    const int prevt  = dir ? (t + 1) : (t - 1);   // matches jj only when s>0
    const int prevt2 = dir ? (t + 2) : (t - 2);
    const int par = s & 1;

    // ---- (A2) precompute relative-agg term for the jj != prevt case ----
    const float gv_base = (jjU == prevt2) ? gprev : Gg;
    const float sm_pre  = mkU ? (sigmf(gv_base + p5 + LBg) * Hg) : 0.0f;

    // ---- (B) rolling depth-3 poll of the 2 owned packets -> perm LDS slots ----
    // s_sleep(2) backoff on the miss path only: cuts IC poll contention
    // (FETCH evidence: ~2.6GB/dispatch of poll fetches on 32 hot lines).
    if (s > 0) {
      const int pb = (((s - 1) & 1) * 2 + dir) * 512;
      u64* q0 = rec + pb + tid;
      u64* q1 = rec + pb + tid + 256;
      u64 a0 = __hip_atomic_load(q0, __ATOMIC_RELAXED, __HIP_MEMORY_SCOPE_AGENT);
      u64 a1 = __hip_atomic_load(q1, __ATOMIC_RELAXED, __HIP_MEMORY_SCOPE_AGENT);
      u64 b0 = __hip_atomic_load(q0, __ATOMIC_RELAXED, __HIP_MEMORY_SCOPE_AGENT);
      u64 b1 = __hip_atomic_load(q1, __ATOMIC_RELAXED, __HIP_MEMORY_SCOPE_AGENT);
      u64 c0 = __hip_atomic_load(q0, __ATOMIC_RELAXED, __HIP_MEMORY_SCOPE_AGENT);
      u64 c1 = __hip_atomic_load(q1, __ATOMIC_RELAXED, __HIP_MEMORY_SCOPE_AGENT);
      for (;;) {
        const bool k0 = (unsigned)(a0 >> 32) >= (unsigned)s;
        const bool k1 = (unsigned)(a1 >> 32) >= (unsigned)s;
        if (k0 && k1) break;
        __builtin_amdgcn_s_sleep(2);   // ~128cyc backoff before resampling
        const u64 n0 = __hip_atomic_load(q0, __ATOMIC_RELAXED, __HIP_MEMORY_SCOPE_AGENT);
        const u64 n1 = __hip_atomic_load(q1, __ATOMIC_RELAXED, __HIP_MEMORY_SCOPE_AGENT);
        a0 = k0 ? a0 : b0;  b0 = k0 ? b0 : c0;  c0 = n0;
        a1 = k1 ? a1 : b1;  b1 = k1 ? b1 : c1;  c1 = n1;
      }
      __hip_atomic_store(&hsp[par][0][tid & 3][tid >> 2], a0,
                         __ATOMIC_RELAXED, __HIP_MEMORY_SCOPE_WORKGROUP);
      __hip_atomic_store(&hsp[par][1][tid & 3][tid >> 2], a1,
                         __ATOMIC_RELAXED, __HIP_MEMORY_SCOPE_WORKGROUP);
    }

    // ---- (B2) per-lane spin on the 8 perm packets (4-way b64 = HW min) ----
    u64 pk0[4], pk1[4];
    for (;;) {
      unsigned mn = 0xffffffffu;
#pragma unroll
      for (int j = 0; j < 4; ++j) {
        pk0[j] = __hip_atomic_load(&hsp[par][0][j][lane],
                                   __ATOMIC_RELAXED, __HIP_MEMORY_SCOPE_WORKGROUP);
        pk1[j] = __hip_atomic_load(&hsp[par][1][j][lane],
                                   __ATOMIC_RELAXED, __HIP_MEMORY_SCOPE_WORKGROUP);
        const unsigned t0 = (unsigned)(pk0[j] >> 32);
        const unsigned t1 = (unsigned)(pk1[j] >> 32);
        mn = mn < t0 ? mn : t0;
        mn = mn < t1 ? mn : t1;
      }
      if (mn >= (unsigned)s) break;
    }

    // ---- (C) dots: 6 owned rows x 8 elems/lane, butterfly over 64 lanes ----
    float hx0[4], hx1[4];
#pragma unroll
    for (int j = 0; j < 4; ++j) {
      hx0[j] = __uint_as_float((unsigned)pk0[j]);
      hx1[j] = __uint_as_float((unsigned)pk1[j]);
    }
    float dsum[6];
#pragma unroll
    for (int rg = 0; rg < 6; ++rg) {
      float a = 0.0f;
#pragma unroll
      for (int j = 0; j < 4; ++j) {
        a += wreg[rg][0][j] * hx0[j];
        a += wreg[rg][1][j] * hx1[j];
      }
      a += __shfl_xor(a, 1);  a += __shfl_xor(a, 2);  a += __shfl_xor(a, 4);
      a += __shfl_xor(a, 8);  a += __shfl_xor(a, 16); a += __shfl_xor(a, 32);
      dsum[rg] = a;            // full sum in ALL 64 lanes
    }
    const float g = dsum[5];   // Wlh @ h_prev = G[prevt]

    // ---- (D) gates + relative aggregation (identical on all lanes) ----
    const float iv = sigmf(p0 + dsum[0]);
    const float ov = sigmf(p1 + dsum[1]);
    const float sv = sigmf(p2 + dsum[2]);
    const float fv = sigmf(p3 + dsum[3]);
    const float uv = tanhfast(p4 + dsum[4]);
    cstate = fv * cstate + iv * uv;
    const float hb = ov * tanhfast(cstate);

    const float smf = mkU ? (sigmf(g + p5 + LBg) * hprev) : 0.0f;  // jj==prevt patch
    float sm = (jjU == prevt) ? smf : sm_pre;
    sm += __shfl_xor(sm, 1); sm += __shfl_xor(sm, 2); sm += __shfl_xor(sm, 4);
    const float hval = hb + sv * tanhfast(sm);

    // ---- (E) publish first (critical path), then plain stores ----
    if (lane == 0) {
      const u64 pk =
          ((u64)(unsigned)(s + 1) << 32) | (u64)__float_as_uint(hval);
      __hip_atomic_store(rec + ((s & 1) * 2 + dir) * 512 + m, pk,
                         __ATOMIC_RELAXED, __HIP_MEMORY_SCOPE_AGENT);
      out[(size_t)t * 1024 + dircol + m] = hval;
      if (s > 0) Gbuf[(size_t)prevt * 512 + m] = g;
    }

    // ---- (F) prefetch next step: 1-deep chains (indices already in regs) ----
    if (s < S_LEN - 1) {
      const float HgN  = out[(size_t)jjN * 1024 + dircol + m];
      const float GgN  = Gbuf[(size_t)jjN * 512 + m];
      const float LBgN = lb[(size_t)depN * 512 + m];
      const float* prow = P + (size_t)tn * 3072;
      p0 = prow[m];        p1 = prow[512 + m];  p2 = prow[1024 + m];
      p3 = prow[1536 + m]; p4 = prow[2048 + m]; p5 = prow[2560 + m];
      int jj2 = jjN, mk2 = mkN, dep2 = depN;
      if (s < S_LEN - 2) {
        const int t2 = dir ? (t - 2) : (t + 2);
        jj2 = rel[t2 * KREL + kl]; mk2 = (int)msk[t2 * KREL + kl]; dep2 = dep[t2 * KREL + kl];
      }
      jjU = jjN; mkU = mkN; Hg = HgN; Gg = GgN; LBg = LBgN;
      jjN = jj2; mkN = mk2; depN = dep2;
    }
    hprev = hval; gprev = g;
  }
}

__global__ void k_fill(float* __restrict__ o, int n, float v)
{ const int i = blockIdx.x * 256 + threadIdx.x; if (i < n) o[i] = v; }

extern "C" void kernel_launch(void* const* d_in, const int* in_sizes, int n_in,
                              void* d_out, int out_size, void* d_ws, size_t ws_size,
                              hipStream_t stream)
{
  (void)in_sizes; (void)n_in;
  const float* X     = (const float*)d_in[0];
  const float* Wioux = (const float*)d_in[1];
  const float* bioux = (const float*)d_in[2];
  const float* Wiouh = (const float*)d_in[3];
  const float* biouh = (const float*)d_in[4];
  const float* Wlx   = (const float*)d_in[5];
  const float* blx   = (const float*)d_in[6];
  const float* Wlh   = (const float*)d_in[7];
  const float* blh   = (const float*)d_in[8];
  const float* lb    = (const float*)d_in[9];
  const int* rel_fw  = (const int*)d_in[10];
  const int* dep_fw  = (const int*)d_in[11];
  const unsigned char* mask_fw_raw = (const unsigned char*)d_in[12];
  const int* rel_bw  = (const int*)d_in[13];
  const int* dep_bw  = (const int*)d_in[14];
  const unsigned char* mask_bw_raw = (const unsigned char*)d_in[15];
  float* out = (float*)d_out;

  const int nmask = S_LEN * KREL;                  // 65536
  const size_t needP = (size_t)S_LEN * 3072 * 4;   // 96 MB
  const size_t needG = (size_t)S_LEN * 512 * 4;    // 16 MB each
  const size_t need  = 32768 + needP + 2 * needG + 2 * (size_t)nmask;
  if (ws_size < need) {
    k_fill<<<(out_size + 255) / 256, 256, 0, stream>>>(out, out_size, 12345.0f);
    return;
  }
  char* ws = (char*)d_ws;
  u64*   rec = (u64*)ws;                   // [2 buf][2 dir][512] packets
  float* P   = (float*)(ws + 32768);
  float* Gfw = (float*)(ws + 32768 + needP);
  float* Gbw = Gfw + (size_t)S_LEN * 512;
  unsigned char* Mfw = (unsigned char*)(ws + 32768 + needP + 2 * needG);
  unsigned char* Mbw = Mfw + nmask;

  hipMemsetAsync(rec, 0, 16384, stream);   // tags must start at 0 (ws poisoned 0xAA)
  k_maskcvt<<<64, 256, 0, stream>>>(mask_fw_raw, Mfw, nmask);
  k_maskcvt<<<64, 256, 0, stream>>>(mask_bw_raw, Mbw, nmask);
  dim3 gg(S_LEN / 64, 3072 / 64);
  k_gemm<<<gg, 256, 0, stream>>>(X, Wioux, Wlx, bioux, biouh, blx, blh, P);
  k_rec<<<2 * WPD, 256, 0, stream>>>(Wiouh, Wlh, P, lb, rel_fw, dep_fw, Mfw,
                                     rel_bw, dep_bw, Mbw, Gfw, Gbw, rec, out);
}